// Round 2
// 717.369 us; speedup vs baseline: 1.2331x; 1.2331x over previous
//
#include <hip/hip_runtime.h>
#include <hip/hip_bf16.h>
#include <cstdint>
#include <cstddef>

#define B_ 64
#define T_ 2048
// LDS row stride (elements). 40*2B = 80B = 20 banks: b128 reads across 16 rows
// alias only 2-way (free per m136). 32 (64B) was an 8-way conflict (6.4M SQ_LDS_BANK_CONFLICT).
#define LDP 40

typedef unsigned short ushort_t;
typedef __attribute__((ext_vector_type(8))) short bf16x8;   // 8 bf16 (4 VGPRs)
typedef __attribute__((ext_vector_type(4))) float f32x4;    // MFMA C/D

__device__ __forceinline__ float sigmoidf_(float x){ return 1.f/(1.f+__expf(-x)); }
__device__ __forceinline__ float tanhf_(float x){
  x = fminf(fmaxf(x,-15.f),15.f);
  float e = __expf(2.f*x);
  return (e-1.f)/(e+1.f);
}

// RNE fp32->bf16 pair packed into one dword
__device__ __forceinline__ unsigned f2b_pair(float lo, float hi){
  unsigned a = __float_as_uint(lo), b = __float_as_uint(hi);
  a += 0x7FFFu + ((a>>16)&1u);
  b += 0x7FFFu + ((b>>16)&1u);
  return (a>>16) | (b & 0xFFFF0000u);
}
__device__ __forceinline__ uint4 pack8(float4 x, float4 y){
  uint4 v;
  v.x = f2b_pair(x.x, x.y);
  v.y = f2b_pair(x.z, x.w);
  v.z = f2b_pair(y.x, y.y);
  v.w = f2b_pair(y.z, y.w);
  return v;
}

// rel_table[r][j] = rel_emb[r] . rel_w_ih[j] + rel_b_ih[j], r<64, j<768  (fp32)
__global__ __launch_bounds__(256)
void table_kernel(const float* __restrict__ rel_emb, const float* __restrict__ w_ih,
                  const float* __restrict__ b_ih, float* __restrict__ table)
{
  int idx = blockIdx.x*256 + threadIdx.x;   // < 64*768
  int r = idx/768, j = idx - r*768;
  const float* e = rel_emb + (size_t)r*256;
  const float* w = w_ih   + (size_t)j*256;
  float acc = 0.f;
  for(int k=0;k<256;k+=4){
    float4 ev = *(const float4*)(e+k);
    float4 wv = *(const float4*)(w+k);
    acc = fmaf(ev.x,wv.x,acc); acc = fmaf(ev.y,wv.y,acc);
    acc = fmaf(ev.z,wv.z,acc); acc = fmaf(ev.w,wv.w,acc);
  }
  table[idx] = acc + b_ih[j];
}

// convert the three 768x256 weight matrices to bf16 (row-major, K contiguous)
__global__ __launch_bounds__(256)
void wcvt_kernel(const float* __restrict__ a, const float* __restrict__ b, const float* __restrict__ c,
                 ushort_t* __restrict__ oa, ushort_t* __restrict__ ob, ushort_t* __restrict__ oc)
{
  int i = blockIdx.x*256 + threadIdx.x;     // < 3*24576
  int seg = i / 24576;
  int off = (i - seg*24576) * 8;
  const float* s; ushort_t* d;
  if(seg==0){ s=a; d=oa; } else if(seg==1){ s=b; d=ob; } else { s=c; d=oc; }
  float4 x = *(const float4*)(s+off), y = *(const float4*)(s+off+4);
  *(uint4*)(d+off) = pack8(x,y);
}

// ---------------------------------------------------------------------------
// MFMA GEMM+GRU kernels.
// Tile: 128 rows x (3 gates x 64 cols).  Grid = (ceil(M/128), 4).
// LDS: As[128][LDP] bf16 (A rows, k-contig), Bs[192][LDP] bf16 (W rows: gate*64+n).
// Wave w owns rows w*32..w*32+31: 2 m-tiles x 12 n-tiles of 16x16x32 MFMA.
// C/D layout (m89-verified): col = lane&15, row = (lane>>4)*4 + reg.
// Round 1 changes: LDS pad 32->40 (bank conflicts), register prefetch of the
// next k-step's global loads under the current step's LDS+MFMA phase, and
// run-merged atomics in the msg epilogue (sibling rows are contiguous -> the
// 4 rows a lane holds usually share a parent mailbox pointer).
// ---------------------------------------------------------------------------

template<bool LEAF>
__global__ __launch_bounds__(256)
void node_mfma(const float* __restrict__ embs, const float* __restrict__ red,
               const ushort_t* __restrict__ wih, const ushort_t* __restrict__ whh,
               const float* __restrict__ b_ih, const float* __restrict__ b_hh,
               float* __restrict__ out, int t_lo, unsigned cnt, unsigned Mtot)
{
  __shared__ ushort_t As[128][LDP];
  __shared__ ushort_t Bs[192][LDP];
  const int tid  = threadIdx.x;
  const unsigned Mbase = blockIdx.x*128u;
  const int nb   = blockIdx.y;          // 64-col block within each gate
  const int lane = tid & 63, w = tid >> 6;
  const int quad = lane >> 4, cl = lane & 15;

  // staging assignment: thread -> (row tid>>2 [+64], 8 k's at (tid&3)*8)
  const int srow = tid >> 2;
  const int g8   = (tid & 3) * 8;
  unsigned r0 = Mbase + srow;      if(r0 > Mtot-1) r0 = Mtot-1;
  unsigned r1 = Mbase + srow + 64; if(r1 > Mtot-1) r1 = Mtot-1;
  unsigned b0v = r0 / cnt, t0v = (unsigned)t_lo + (r0 - b0v*cnt);
  unsigned b1v = r1 / cnt, t1v = (unsigned)t_lo + (r1 - b1v*cnt);
  const float* x0p = embs + ((size_t)b0v*T_ + t0v)*256 + g8;
  const float* x1p = embs + ((size_t)b1v*T_ + t1v)*256 + g8;
  const float* rd0p = red + ((size_t)b0v*256 + t0v)*256 + g8;
  const float* rd1p = red + ((size_t)b1v*256 + t1v)*256 + g8;
  // B staging: issue e stages LDS rows e*64+srow  <- W row e*256 + nb*64 + srow
  const size_t woff0 = ((size_t)(0*256 + nb*64 + srow))*256 + g8;
  const size_t woff1 = ((size_t)(1*256 + nb*64 + srow))*256 + g8;
  const size_t woff2 = ((size_t)(2*256 + nb*64 + srow))*256 + g8;

  f32x4 acc[2][12];
  f32x4 accN2[2][4];
  const f32x4 zz = {0.f,0.f,0.f,0.f};
  #pragma unroll
  for(int i=0;i<2;i++){
    #pragma unroll
    for(int j=0;j<12;j++) acc[i][j] = zz;
    #pragma unroll
    for(int j=0;j<4;j++) accN2[i][j] = zz;
  }

  const int KSTOT = LEAF ? 256 : 512;   // pass 0: x @ wih ; pass 1: red @ whh
  float4 ax0,ay0,ax1,ay1; uint4 w0,w1,w2;

#define NLOAD(KS) do{ \
    const int kk_ = (KS) & 255; \
    const float* A0_ = (LEAF || (KS) < 256) ? x0p : rd0p; \
    const float* A1_ = (LEAF || (KS) < 256) ? x1p : rd1p; \
    const ushort_t* W_ = (LEAF || (KS) < 256) ? wih : whh; \
    ax0 = *(const float4*)(A0_+kk_); ay0 = *(const float4*)(A0_+kk_+4); \
    ax1 = *(const float4*)(A1_+kk_); ay1 = *(const float4*)(A1_+kk_+4); \
    w0 = *(const uint4*)(W_+woff0+kk_); \
    w1 = *(const uint4*)(W_+woff1+kk_); \
    w2 = *(const uint4*)(W_+woff2+kk_); \
  }while(0)

  NLOAD(0);
  #pragma unroll 1
  for(int ks=0; ks<KSTOT; ks+=32){
    __syncthreads();                       // prev step's LDS readers done
    *(uint4*)&As[srow     ][g8] = pack8(ax0, ay0);
    *(uint4*)&As[srow + 64][g8] = pack8(ax1, ay1);
    *(uint4*)&Bs[srow      ][g8] = w0;
    *(uint4*)&Bs[srow +  64][g8] = w1;
    *(uint4*)&Bs[srow + 128][g8] = w2;
    __syncthreads();
    if(ks + 32 < KSTOT) NLOAD(ks + 32);    // prefetch: HBM latency hides under ds_read+MFMA
    const bool p1 = (!LEAF) && (ks >= 256);
    bf16x8 af0 = *(const bf16x8*)&As[w*32      + cl][quad*8];
    bf16x8 af1 = *(const bf16x8*)&As[w*32 + 16 + cl][quad*8];
    #pragma unroll
    for(int j=0;j<12;j++){
      bf16x8 bfj = *(const bf16x8*)&Bs[j*16 + cl][quad*8];
      if(j>=8 && p1){
        accN2[0][j-8] = __builtin_amdgcn_mfma_f32_16x16x32_bf16(af0, bfj, accN2[0][j-8], 0,0,0);
        accN2[1][j-8] = __builtin_amdgcn_mfma_f32_16x16x32_bf16(af1, bfj, accN2[1][j-8], 0,0,0);
      } else {
        acc[0][j] = __builtin_amdgcn_mfma_f32_16x16x32_bf16(af0, bfj, acc[0][j], 0,0,0);
        acc[1][j] = __builtin_amdgcn_mfma_f32_16x16x32_bf16(af1, bfj, acc[1][j], 0,0,0);
      }
    }
  }
#undef NLOAD

  // epilogue: GRU combine, fp32 store (clamped duplicate rows write same value)
  float bir[4],biz[4],bin[4],bhr[4],bhz[4],bhn[4];
  #pragma unroll
  for(int c=0;c<4;c++){
    int col = nb*64 + c*16 + cl;
    bir[c]=b_ih[col]; biz[c]=b_ih[256+col]; bin[c]=b_ih[512+col];
    bhr[c]=b_hh[col]; bhz[c]=b_hh[256+col]; bhn[c]=b_hh[512+col];
  }
  #pragma unroll
  for(int i=0;i<2;i++){
    #pragma unroll
    for(int r=0;r<4;r++){
      unsigned gm = Mbase + (unsigned)(w*32 + i*16 + quad*4 + r);
      if(gm > Mtot-1) gm = Mtot-1;
      unsigned b = gm / cnt, t = (unsigned)t_lo + (gm - b*cnt);
      float* orow = out + ((size_t)b*T_ + t)*256;
      const float* rr = red + ((size_t)b*256 + t)*256;
      #pragma unroll
      for(int c=0;c<4;c++){
        int col = nb*64 + c*16 + cl;
        float gr = acc[i][c][r]   + bir[c] + bhr[c];
        float gz = acc[i][4+c][r] + biz[c] + bhz[c];
        float gni = acc[i][8+c][r] + bin[c];
        float hn  = (LEAF ? 0.f : accN2[i][c][r]) + bhn[c];
        float rg = sigmoidf_(gr);
        float zg = sigmoidf_(gz);
        float ng = tanhf_(gni + rg*hn);
        float rv = LEAF ? 0.f : rr[col];
        orow[col] = (1.f-zg)*ng + zg*rv;
      }
    }
  }
}

// msg: gates = table[rel] (gi) + h @ rel_w_hh^T + rel_b_hh; red[parent] += msg
__global__ __launch_bounds__(256)
void msg_mfma(const float* __restrict__ hbuf, const ushort_t* __restrict__ wbf,
              const float* __restrict__ b_hh, const float* __restrict__ table,
              const int* __restrict__ rels, float* __restrict__ red,
              int t_lo, unsigned cnt, unsigned Mtot)
{
  __shared__ ushort_t As[128][LDP];
  __shared__ ushort_t Bs[192][LDP];
  const int tid  = threadIdx.x;
  const unsigned Mbase = blockIdx.x*128u;
  const int nb   = blockIdx.y;
  const int lane = tid & 63, w = tid >> 6;
  const int quad = lane >> 4, cl = lane & 15;

  const int srow = tid >> 2;
  const int g8   = (tid & 3) * 8;
  unsigned r0 = Mbase + srow;      if(r0 > Mtot-1) r0 = Mtot-1;
  unsigned r1 = Mbase + srow + 64; if(r1 > Mtot-1) r1 = Mtot-1;
  unsigned b0v = r0 / cnt, t0v = (unsigned)t_lo + (r0 - b0v*cnt);
  unsigned b1v = r1 / cnt, t1v = (unsigned)t_lo + (r1 - b1v*cnt);
  const float* a0 = hbuf + ((size_t)b0v*T_ + t0v)*256 + g8;
  const float* a1 = hbuf + ((size_t)b1v*T_ + t1v)*256 + g8;
  const size_t woff0 = ((size_t)(0*256 + nb*64 + srow))*256 + g8;
  const size_t woff1 = ((size_t)(1*256 + nb*64 + srow))*256 + g8;
  const size_t woff2 = ((size_t)(2*256 + nb*64 + srow))*256 + g8;

  f32x4 acc[2][12];
  const f32x4 zz = {0.f,0.f,0.f,0.f};
  #pragma unroll
  for(int i=0;i<2;i++)
    #pragma unroll
    for(int j=0;j<12;j++) acc[i][j] = zz;

  float4 ax0,ay0,ax1,ay1; uint4 w0,w1,w2;

#define MLOAD(KK) do{ \
    ax0 = *(const float4*)(a0+(KK)); ay0 = *(const float4*)(a0+(KK)+4); \
    ax1 = *(const float4*)(a1+(KK)); ay1 = *(const float4*)(a1+(KK)+4); \
    w0 = *(const uint4*)(wbf+woff0+(KK)); \
    w1 = *(const uint4*)(wbf+woff1+(KK)); \
    w2 = *(const uint4*)(wbf+woff2+(KK)); \
  }while(0)

  MLOAD(0);
  #pragma unroll 1
  for(int kk=0; kk<256; kk+=32){
    __syncthreads();
    *(uint4*)&As[srow     ][g8] = pack8(ax0, ay0);
    *(uint4*)&As[srow + 64][g8] = pack8(ax1, ay1);
    *(uint4*)&Bs[srow      ][g8] = w0;
    *(uint4*)&Bs[srow +  64][g8] = w1;
    *(uint4*)&Bs[srow + 128][g8] = w2;
    __syncthreads();
    if(kk + 32 < 256) MLOAD(kk + 32);
    bf16x8 af0 = *(const bf16x8*)&As[w*32      + cl][quad*8];
    bf16x8 af1 = *(const bf16x8*)&As[w*32 + 16 + cl][quad*8];
    #pragma unroll
    for(int j=0;j<12;j++){
      bf16x8 bfj = *(const bf16x8*)&Bs[j*16 + cl][quad*8];
      acc[0][j] = __builtin_amdgcn_mfma_f32_16x16x32_bf16(af0, bfj, acc[0][j], 0,0,0);
      acc[1][j] = __builtin_amdgcn_mfma_f32_16x16x32_bf16(af1, bfj, acc[1][j], 0,0,0);
    }
  }
#undef MLOAD

  float bhr[4],bhz[4],bhn[4];
  #pragma unroll
  for(int c=0;c<4;c++){
    int col = nb*64 + c*16 + cl;
    bhr[c]=b_hh[col]; bhz[c]=b_hh[256+col]; bhn[c]=b_hh[512+col];
  }
  #pragma unroll
  for(int i=0;i<2;i++){
    // per-row info for the 4 consecutive rows this lane holds
    float* rp[4]; bool okr[4]; const float* tb[4]; const float* hrp[4];
    #pragma unroll
    for(int r=0;r<4;r++){
      unsigned gm = Mbase + (unsigned)(w*32 + i*16 + quad*4 + r);
      okr[r] = (gm < Mtot);               // clamped duplicates must not contribute
      if(gm > Mtot-1) gm = Mtot-1;
      unsigned b = gm / cnt, t = (unsigned)t_lo + (gm - b*cnt);
      int rel = rels[(size_t)b*T_ + t];
      tb[r]  = table + (size_t)rel*768;
      hrp[r] = hbuf + ((size_t)b*T_ + t)*256;
      rp[r]  = red + ((size_t)b*256 + ((t-1)>>3))*256;
    }
    float mv[4][4];
    #pragma unroll
    for(int r=0;r<4;r++){
      #pragma unroll
      for(int c=0;c<4;c++){
        int col = nb*64 + c*16 + cl;
        float gr  = tb[r][col]     + acc[i][c][r]   + bhr[c];
        float gz  = tb[r][256+col] + acc[i][4+c][r] + bhz[c];
        float gnh = acc[i][8+c][r] + bhn[c];
        float rg = sigmoidf_(gr);
        float zg = sigmoidf_(gz);
        float ng = tanhf_(tb[r][512+col] + rg*gnh);
        mv[r][c] = (1.f-zg)*ng + zg*hrp[r][col];
      }
    }
    // run-merged atomics: siblings are contiguous rows -> consecutive r often
    // share the same parent mailbox row pointer; merge before the atomicAdd.
    // (Pointer-equality merge is correctness-neutral for any tree shape.)
    #pragma unroll
    for(int c=0;c<4;c++){
      int col = nb*64 + c*16 + cl;
      float a = 0.f; bool any = false;
      #pragma unroll
      for(int r=0;r<4;r++){
        if(okr[r]){ a += mv[r][c]; any = true; }
        bool flush;
        if(r==3) flush = true; else flush = (rp[r+1] != rp[r]);
        if(flush){
          if(any) atomicAdd(rp[r] + col, a);
          a = 0.f; any = false;
        }
      }
    }
  }
}

extern "C" void kernel_launch(void* const* d_in, const int* in_sizes, int n_in,
                              void* d_out, int out_size, void* d_ws, size_t ws_size,
                              hipStream_t stream)
{
  const float* embs    = (const float*)d_in[0];
  const float* rel_emb = (const float*)d_in[1];
  const float* nwih    = (const float*)d_in[2];
  const float* nwhh    = (const float*)d_in[3];
  const float* nbih    = (const float*)d_in[4];
  const float* nbhh    = (const float*)d_in[5];
  const float* rwih    = (const float*)d_in[6];
  const float* rwhh    = (const float*)d_in[7];
  const float* rbih    = (const float*)d_in[8];
  const float* rbhh    = (const float*)d_in[9];
  const int*   rels    = (const int*)d_in[11];
  float* out = (float*)d_out;

  float* red   = (float*)d_ws;              // [64][256][256] fp32 mailbox
  float* table = red + (size_t)4194304;     // [64][768] fp32
  ushort_t* wih_bf  = (ushort_t*)(table + 49152);
  ushort_t* whh_bf  = wih_bf + 196608;
  ushort_t* rwhh_bf = whh_bf + 196608;

  hipMemsetAsync(red, 0, (size_t)4194304*4, stream);
  table_kernel<<<dim3(192), 256, 0, stream>>>(rel_emb, rwih, rbih, table);
  wcvt_kernel<<<dim3(288), 256, 0, stream>>>(nwih, nwhh, rwhh, wih_bf, whh_bf, rwhh_bf);

  // topological levels of the deterministic 8-ary heap over 2048 nodes
  const int      tlo[5] = {256, 32, 4, 1, 0};
  const unsigned cntv[5]= {1792, 224, 28, 3, 1};
  const unsigned Mv[5]  = {114688, 14336, 1792, 192, 64};

  for(int L=0; L<5; L++){
    dim3 g((Mv[L]+127)/128, 4);
    if(L==0)
      node_mfma<true ><<<g, 256, 0, stream>>>(embs, red, wih_bf, whh_bf, nbih, nbhh, out, tlo[L], cntv[L], Mv[L]);
    else
      node_mfma<false><<<g, 256, 0, stream>>>(embs, red, wih_bf, whh_bf, nbih, nbhh, out, tlo[L], cntv[L], Mv[L]);
    if(L < 4)
      msg_mfma<<<g, 256, 0, stream>>>(out, rwhh_bf, rbhh, table, rels, red, tlo[L], cntv[L], Mv[L]);
  }
}